// Round 6
// baseline (513.786 us; speedup 1.0000x reference)
//
#include <hip/hip_runtime.h>
#include <math.h>

#define STEPS 37
#define NMAT  (STEPS*STEPS + 1)   // 1370
#define D     128
#define NT    1024                // 16 waves, 4 per SIMD

typedef _Float16 half8 __attribute__((ext_vector_type(8)));
typedef __fp16   fp16x2 __attribute__((ext_vector_type(2)));
typedef float    f32x4 __attribute__((ext_vector_type(4)));

// Two 64KB fp16-split matrix regions, swizzled 256B rows (16 slots of 16B,
// slot ^= row&7):  R0 = P row-major, later X row-major (A-operand)
//                  R1 = X^T (B-operand, K-contiguous)
// During Horner, X^T ping-pongs between R0 and R1 (P lives in registers).
#define R0H 0
#define R0L 32768
#define R1H 65536
#define R1L 98304
#define RED_OFF 131072
#define LDS_BYTES (131072 + 640)

// Taylor 1/k!, degree 7 (theta = 0.5)
__constant__ float dC[8] = {
    1.0f, 1.0f, 5.0e-1f, 1.6666666666666666e-1f, 4.1666666666666664e-2f,
    8.3333333333333332e-3f, 1.3888888888888889e-3f, 1.9841269841269841e-4f };

__device__ __forceinline__ int swzA(int r, int slot) {       // 16B-slot address
    return r*256 + ((slot ^ (r & 7)) << 4);
}
__device__ __forceinline__ int swzE(int r, int c) {          // element address
    return r*256 + (((c >> 3) ^ (r & 7)) << 4) + ((c & 7) << 1);
}

__device__ __forceinline__ void conv_tile(const f32x4 a1, const f32x4 a2,
                                          float diagc, bool hasdiag,
                                          int r0, int col, uint2& uh, uint2& ul)
{
    float v[4];
    #pragma unroll
    for (int q = 0; q < 4; ++q) v[q] = a1[q] + a2[q] * (1.0f/2048.0f);
    if (hasdiag) {
        #pragma unroll
        for (int q = 0; q < 4; ++q) if (r0 + q == col) v[q] += diagc;
    }
    const fp16x2 h01 = __builtin_amdgcn_cvt_pkrtz(v[0], v[1]);
    const fp16x2 h23 = __builtin_amdgcn_cvt_pkrtz(v[2], v[3]);
    const fp16x2 l01 = __builtin_amdgcn_cvt_pkrtz((v[0]-(float)h01[0])*2048.f,
                                                  (v[1]-(float)h01[1])*2048.f);
    const fp16x2 l23 = __builtin_amdgcn_cvt_pkrtz((v[2]-(float)h23[0])*2048.f,
                                                  (v[3]-(float)h23[1])*2048.f);
    union { fp16x2 h2[2]; uint2 u; } ch, cl;
    ch.h2[0] = h01; ch.h2[1] = h23;
    cl.h2[0] = l01; cl.h2[1] = l23;
    uh = ch.u; ul = cl.u;
}

// Horner step: Y = P*X + diagc*I. P from cached regs; X^T from src; Y^T -> dst.
// LAST also writes Y row-major into src region (needs a read-done barrier).
template<bool LAST>
__device__ __forceinline__ void horner_step(unsigned char* sm,
                                            int srcH, int srcL, int dstH, int dstL,
                                            const half8 (&pah)[2][4], const half8 (&pal)[2][4],
                                            float diagc, int wr, int wc, int lr, int g)
{
    f32x4 acc1[2][2] = {};
    f32x4 acc2[2][2] = {};
    #pragma unroll
    for (int ks = 0; ks < 4; ++ks) {
        const int slot = 4*ks + g;
        #pragma unroll
        for (int bj = 0; bj < 2; ++bj) {
            const int c = wc*32 + bj*16 + lr;
            const int off = swzA(c, slot);
            const half8 qh = *(const half8*)(sm + srcH + off);
            const half8 ql = *(const half8*)(sm + srcL + off);
            #pragma unroll
            for (int bi = 0; bi < 2; ++bi) {
                acc1[bi][bj] = __builtin_amdgcn_mfma_f32_16x16x32_f16(pah[bi][ks], qh, acc1[bi][bj], 0, 0, 0);
                acc2[bi][bj] = __builtin_amdgcn_mfma_f32_16x16x32_f16(pah[bi][ks], ql, acc2[bi][bj], 0, 0, 0);
                acc2[bi][bj] = __builtin_amdgcn_mfma_f32_16x16x32_f16(pal[bi][ks], qh, acc2[bi][bj], 0, 0, 0);
            }
        }
    }
    uint2 uh[2][2], ul[2][2];
    #pragma unroll
    for (int bi = 0; bi < 2; ++bi)
        #pragma unroll
        for (int bj = 0; bj < 2; ++bj) {
            const int col = wc*32 + bj*16 + lr;
            const int r0  = wr*32 + bi*16 + 4*g;
            conv_tile(acc1[bi][bj], acc2[bi][bj], diagc,
                      wr*32 + bi*16 == wc*32 + bj*16, r0, col, uh[bi][bj], ul[bi][bj]);
        }
    if (LAST) __syncthreads();          // src reads done before Xrow lands in src
    #pragma unroll
    for (int bi = 0; bi < 2; ++bi)
        #pragma unroll
        for (int bj = 0; bj < 2; ++bj) {
            const int col = wc*32 + bj*16 + lr;
            const int r0  = wr*32 + bi*16 + 4*g;
            const int offQ = col*256 + (((r0 >> 3) ^ (col & 7)) << 4) + ((g & 1) << 3);
            *(uint2*)(sm + dstH + offQ) = uh[bi][bj];
            *(uint2*)(sm + dstL + offQ) = ul[bi][bj];
            if (LAST) {                 // X row-major into src region (scatter)
                union { uint2 u; _Float16 h[4]; } th, tl;
                th.u = uh[bi][bj]; tl.u = ul[bi][bj];
                #pragma unroll
                for (int q = 0; q < 4; ++q) {
                    const int off = swzE(r0 + q, col);
                    *(_Float16*)(sm + srcH + off) = th.h[q];
                    *(_Float16*)(sm + srcL + off) = tl.h[q];
                }
            }
        }
    __syncthreads();
}

// Squaring step: Y = X*X. A-frags from R0 (Xrow), B-frags from R1 (X^T), in place.
template<bool WGL>
__device__ __forceinline__ void square_step(unsigned char* sm, float* __restrict__ gout,
                                            int wr, int wc, int lr, int g)
{
    f32x4 acc1[2][2] = {};
    f32x4 acc2[2][2] = {};
    #pragma unroll
    for (int ks = 0; ks < 4; ++ks) {
        const int slot = 4*ks + g;
        half8 ah[2], al[2];
        #pragma unroll
        for (int bi = 0; bi < 2; ++bi) {
            const int r = wr*32 + bi*16 + lr;
            const int off = swzA(r, slot);
            ah[bi] = *(const half8*)(sm + R0H + off);
            al[bi] = *(const half8*)(sm + R0L + off);
        }
        #pragma unroll
        for (int bj = 0; bj < 2; ++bj) {
            const int c = wc*32 + bj*16 + lr;
            const int off = swzA(c, slot);
            const half8 qh = *(const half8*)(sm + R1H + off);
            const half8 ql = *(const half8*)(sm + R1L + off);
            #pragma unroll
            for (int bi = 0; bi < 2; ++bi) {
                acc1[bi][bj] = __builtin_amdgcn_mfma_f32_16x16x32_f16(ah[bi], qh, acc1[bi][bj], 0, 0, 0);
                acc2[bi][bj] = __builtin_amdgcn_mfma_f32_16x16x32_f16(ah[bi], ql, acc2[bi][bj], 0, 0, 0);
                acc2[bi][bj] = __builtin_amdgcn_mfma_f32_16x16x32_f16(al[bi], qh, acc2[bi][bj], 0, 0, 0);
            }
        }
    }
    if (WGL) {
        #pragma unroll
        for (int bi = 0; bi < 2; ++bi)
            #pragma unroll
            for (int bj = 0; bj < 2; ++bj) {
                const int col = wc*32 + bj*16 + lr;
                const int r0  = wr*32 + bi*16 + 4*g;
                #pragma unroll
                for (int q = 0; q < 4; ++q)
                    gout[(r0+q)*D + col] = acc1[bi][bj][q] + acc2[bi][bj][q] * (1.0f/2048.0f);
            }
        return;
    }
    uint2 uh[2][2], ul[2][2];
    #pragma unroll
    for (int bi = 0; bi < 2; ++bi)
        #pragma unroll
        for (int bj = 0; bj < 2; ++bj) {
            const int col = wc*32 + bj*16 + lr;
            const int r0  = wr*32 + bi*16 + 4*g;
            conv_tile(acc1[bi][bj], acc2[bi][bj], 0.f, false, r0, col, uh[bi][bj], ul[bi][bj]);
        }
    __syncthreads();   // all reads done before in-place overwrite
    #pragma unroll
    for (int bi = 0; bi < 2; ++bi)
        #pragma unroll
        for (int bj = 0; bj < 2; ++bj) {
            const int col = wc*32 + bj*16 + lr;
            const int r0  = wr*32 + bi*16 + 4*g;
            const int offQ = col*256 + (((r0 >> 3) ^ (col & 7)) << 4) + ((g & 1) << 3);
            *(uint2*)(sm + R1H + offQ) = uh[bi][bj];
            *(uint2*)(sm + R1L + offQ) = ul[bi][bj];
            union { uint2 u; _Float16 h[4]; } th, tl;
            th.u = uh[bi][bj]; tl.u = ul[bi][bj];
            #pragma unroll
            for (int q = 0; q < 4; ++q) {
                const int off = swzE(r0 + q, col);
                *(_Float16*)(sm + R0H + off) = th.h[q];
                *(_Float16*)(sm + R0L + off) = tl.h[q];
            }
        }
    __syncthreads();
}

__global__ __launch_bounds__(NT, 4)
void liere_expm_mfma(const float* __restrict__ gen, float* __restrict__ out)
{
    __shared__ __align__(16) unsigned char sm[LDS_BYTES];
    const int tid = threadIdx.x;
    const int wg  = blockIdx.x;

    float px = 0.f, py = 0.f;
    if (wg > 0) {
        const int idx = wg - 1;
        px = (float)(idx / STEPS) * (1.0f/(STEPS-1));
        py = (float)(idx % STEPS) * (1.0f/(STEPS-1));
    }

    // ---- Phase 0: G = px*S0 + py*S1 (fp32), padded 132-float rows at sm+0
    float* Gp = (float*)sm;
    const float* g0 = gen;
    const float* g1 = gen + D*D;
    #pragma unroll
    for (int it = 0; it < 16; ++it) {
        const int e = tid + (it << 10);
        const int i = e >> 7, j = e & 127;
        if (i < j) {
            const float v = px*g0[e] + py*g1[e];
            Gp[i*132 + j] =  v;
            Gp[j*132 + i] = -v;
        } else if (i == j) {
            Gp[i*132 + j] = 0.f;
        }
    }
    __syncthreads();

    // ---- Phase 1: row abs-sums -> tree max -> squaring count (theta = 0.5)
    float* red = (float*)(sm + RED_OFF);
    if (tid < D) {
        float s = 0.f;
        const f32x4* rowp = (const f32x4*)&Gp[tid*132];
        #pragma unroll 8
        for (int u = 0; u < 32; ++u) {
            const f32x4 v = rowp[u];
            s += fabsf(v.x) + fabsf(v.y) + fabsf(v.z) + fabsf(v.w);
        }
        red[tid] = s;
    }
    __syncthreads();
    #pragma unroll
    for (int off = 64; off >= 1; off >>= 1) {
        if (tid < off) red[tid] = fmaxf(red[tid], red[tid + off]);
        __syncthreads();
    }
    const float m = red[0];
    int nsq = 0;
    if (m > 0.5f) nsq = (int)ceilf(log2f(m * 2.0f));
    if (nsq < 0) nsq = 0;
    const float scale = exp2f(-(float)nsq);

    // ---- Phase A: stash this lane's G values (regions about to be reused)
    float vst[16];
    #pragma unroll
    for (int it = 0; it < 16; ++it) {
        const int e = tid + (it << 10);
        vst[it] = Gp[(e>>7)*132 + (e&127)];
    }
    __syncthreads();

    // ---- Phase B: split P = G*2^-s (h, l*2^11): P row-major -> R0,
    //      init X = c7*P + c6*I as X^T -> R1
    {
        const float c7 = dC[7], c6 = dC[6];
        #pragma unroll
        for (int it = 0; it < 16; ++it) {
            const int e = tid + (it << 10);
            const int i = e >> 7, j = e & 127;
            const float p = vst[it] * scale;
            const _Float16 ph = (_Float16)p;
            const _Float16 pl = (_Float16)((p - (float)ph) * 2048.f);
            const int offP = swzE(i, j);
            *(_Float16*)(sm + R0H + offP) = ph;
            *(_Float16*)(sm + R0L + offP) = pl;
            const float x = c7*p + ((i == j) ? c6 : 0.f);
            const _Float16 xh = (_Float16)x;
            const _Float16 xl = (_Float16)((x - (float)xh) * 2048.f);
            const int offQ = swzE(j, i);           // X^T
            *(_Float16*)(sm + R1H + offQ) = xh;
            *(_Float16*)(sm + R1L + offQ) = xl;
        }
    }
    __syncthreads();

    const int lid = tid & 63;
    const int wid = tid >> 6;          // 0..15
    const int wr = wid >> 2, wc = wid & 3;
    const int lr = lid & 15, g = lid >> 4;
    float* gout = out + (size_t)wg * (D*D);

    // ---- cache P's A-fragments in registers (frees R0 for ping-pong)
    half8 pah[2][4], pal[2][4];
    #pragma unroll
    for (int bi = 0; bi < 2; ++bi)
        #pragma unroll
        for (int ks = 0; ks < 4; ++ks) {
            const int r = wr*32 + bi*16 + lr;
            const int off = swzA(r, 4*ks + g);
            pah[bi][ks] = *(const half8*)(sm + R0H + off);
            pal[bi][ks] = *(const half8*)(sm + R0L + off);
        }
    __syncthreads();   // frag loads done before step 1 overwrites R0

    // ---- Horner (deg-7): 5 ping-pong muls + final mul materializing Xrow
    int srcH = R1H, srcL = R1L, dstH = R0H, dstL = R0L;
    for (int kk = 5; kk >= 1; --kk) {
        horner_step<false>(sm, srcH, srcL, dstH, dstL, pah, pal, dC[kk], wr, wc, lr, g);
        int t;
        t = srcH; srcH = dstH; dstH = t;
        t = srcL; srcL = dstL; dstL = t;
    }
    // src = R0, dst = R1: final mul writes X^T -> R1 and Xrow -> R0
    horner_step<true>(sm, srcH, srcL, dstH, dstL, pah, pal, dC[0], wr, wc, lr, g);

    if (nsq == 0) {   // tiny-norm blocks (incl. CLS): Xrow in R0 is the answer
        #pragma unroll
        for (int it = 0; it < 16; ++it) {
            const int e = tid + (it << 10);
            const int i = e >> 7, j = e & 127;
            const int off = swzE(i, j);
            gout[e] = (float)*(_Float16*)(sm + R0H + off)
                    + (float)*(_Float16*)(sm + R0L + off) * (1.0f/2048.0f);
        }
        return;
    }

    // ---- Squarings: X <- X*X; last streams fp32 to HBM
    for (int t = 0; t < nsq - 1; ++t)
        square_step<false>(sm, gout, wr, wc, lr, g);
    square_step<true>(sm, gout, wr, wc, lr, g);
}

extern "C" void kernel_launch(void* const* d_in, const int* in_sizes, int n_in,
                              void* d_out, int out_size, void* d_ws, size_t ws_size,
                              hipStream_t stream) {
    (void)in_sizes; (void)n_in; (void)d_ws; (void)ws_size; (void)out_size;
    const float* gen = (const float*)d_in[1];   // [2,1,128,128] fp32
    float* out = (float*)d_out;                 // [1,1370,1,128,128] fp32
    liere_expm_mfma<<<NMAT, NT, 0, stream>>>(gen, out);
}

// Round 9
// 456.954 us; speedup vs baseline: 1.1244x; 1.1244x over previous
//
#include <hip/hip_runtime.h>
#include <math.h>

#define STEPS 37
#define NMAT  (STEPS*STEPS + 1)   // 1370
#define D     128
#define NT    1024                // 16 waves, 4 per SIMD (hard VGPR cap 128)

typedef _Float16 half8 __attribute__((ext_vector_type(8)));
typedef __fp16   fp16x2 __attribute__((ext_vector_type(2)));
typedef float    f32x4 __attribute__((ext_vector_type(4)));

// Swizzled row-major fp16 matrices: 256B rows (128 halves), 16 slots of 16B,
// slot index XOR'd with (row&7)  -> conflict-free fragment reads (G4/T2).
#define PH_OFF   0          // P high;  later X row-major high  (A-operand)
#define PL_OFF   32768      // P low*2^11; later X row-major low
#define QTH_OFF  65536      // X^T high (B-operand, K-contiguous)
#define QTL_OFF  98304      // X^T low
#define RED_OFF  131072
#define LDS_BYTES (131072 + 640)

// Taylor 1/k!, degree 7 (theta = 0.5)
__constant__ float dC[8] = {
    1.0f, 1.0f, 5.0e-1f, 1.6666666666666666e-1f, 4.1666666666666664e-2f,
    8.3333333333333332e-3f, 1.3888888888888889e-3f, 1.9841269841269841e-4f };

__device__ __forceinline__ int swzA(int r, int slot) {       // 16B-slot address
    return r*256 + ((slot ^ (r & 7)) << 4);
}
__device__ __forceinline__ int swzE(int r, int c) {          // element address
    return r*256 + (((c >> 3) ^ (r & 7)) << 4) + ((c & 7) << 1);
}

// Y = A*X (+ diagc*I). A rows from PH/PL; X cols from QTH/QTL (X^T rows).
// 16 waves: (wr 0..3) x (wc 0..3) own rows [wr*32,+32) x cols [wc*32,+32).
template<bool WQT, bool WXR, bool WGL>
__device__ __forceinline__ void matmul_step(unsigned char* sm, float diagc,
                                            float* __restrict__ gout,
                                            int wr, int wc, int lr, int g)
{
    f32x4 acc1[2][2] = {};   // h*h
    f32x4 acc2[2][2] = {};   // h*l' + l'*h   (l' = l * 2^11)

    #pragma unroll
    for (int ks = 0; ks < 4; ++ks) {
        const int slot = 4*ks + g;             // 16B k-slot within a row
        half8 ah[2], al[2];
        #pragma unroll
        for (int bi = 0; bi < 2; ++bi) {
            const int r = wr*32 + bi*16 + lr;
            const int off = swzA(r, slot);
            ah[bi] = *(const half8*)(sm + PH_OFF + off);
            al[bi] = *(const half8*)(sm + PL_OFF + off);
        }
        #pragma unroll
        for (int bj = 0; bj < 2; ++bj) {
            const int c = wc*32 + bj*16 + lr;
            const int off = swzA(c, slot);
            const half8 qh = *(const half8*)(sm + QTH_OFF + off);
            const half8 ql = *(const half8*)(sm + QTL_OFF + off);
            #pragma unroll
            for (int bi = 0; bi < 2; ++bi) {
                acc1[bi][bj] = __builtin_amdgcn_mfma_f32_16x16x32_f16(ah[bi], qh, acc1[bi][bj], 0, 0, 0);
                acc2[bi][bj] = __builtin_amdgcn_mfma_f32_16x16x32_f16(ah[bi], ql, acc2[bi][bj], 0, 0, 0);
                acc2[bi][bj] = __builtin_amdgcn_mfma_f32_16x16x32_f16(al[bi], qh, acc2[bi][bj], 0, 0, 0);
            }
        }
    }

    if (WGL) {   // last step: stream fp32 to HBM, no LDS writes/barriers
        #pragma unroll
        for (int bi = 0; bi < 2; ++bi)
            #pragma unroll
            for (int bj = 0; bj < 2; ++bj) {
                const int col = wc*32 + bj*16 + lr;
                const int r0  = wr*32 + bi*16 + 4*g;
                #pragma unroll
                for (int q = 0; q < 4; ++q)
                    gout[(r0+q)*D + col] = acc1[bi][bj][q] + acc2[bi][bj][q] * (1.0f/2048.0f);
            }
        return;
    }

    // Register-only split conversion BEFORE the barrier (overlaps other waves' MFMAs)
    uint2 uhv[2][2], ulv[2][2];
    #pragma unroll
    for (int bi = 0; bi < 2; ++bi) {
        #pragma unroll
        for (int bj = 0; bj < 2; ++bj) {
            const int col = wc*32 + bj*16 + lr;
            const int r0  = wr*32 + bi*16 + 4*g;
            float v[4];
            #pragma unroll
            for (int q = 0; q < 4; ++q)
                v[q] = acc1[bi][bj][q] + acc2[bi][bj][q] * (1.0f/2048.0f);
            if (wr*32 + bi*16 == wc*32 + bj*16) {   // wave-uniform: tile holds diagonal
                #pragma unroll
                for (int q = 0; q < 4; ++q)
                    if (r0 + q == col) v[q] += diagc;
            }
            const fp16x2 h01 = __builtin_amdgcn_cvt_pkrtz(v[0], v[1]);
            const fp16x2 h23 = __builtin_amdgcn_cvt_pkrtz(v[2], v[3]);
            const fp16x2 l01 = __builtin_amdgcn_cvt_pkrtz((v[0]-(float)h01[0])*2048.f,
                                                          (v[1]-(float)h01[1])*2048.f);
            const fp16x2 l23 = __builtin_amdgcn_cvt_pkrtz((v[2]-(float)h23[0])*2048.f,
                                                          (v[3]-(float)h23[1])*2048.f);
            union { fp16x2 h2[2]; uint2 u; } cvh, cvl;
            cvh.h2[0] = h01; cvh.h2[1] = h23;
            cvl.h2[0] = l01; cvl.h2[1] = l23;
            uhv[bi][bj] = cvh.u; ulv[bi][bj] = cvl.u;
        }
    }
    __syncthreads();   // all reads of P/X done before overwrite

    #pragma unroll
    for (int bi = 0; bi < 2; ++bi) {
        #pragma unroll
        for (int bj = 0; bj < 2; ++bj) {
            const int col = wc*32 + bj*16 + lr;
            const int r0  = wr*32 + bi*16 + 4*g;
            if (WQT) {   // X^T: b64 at row=col, k-halves r0..r0+3 (swizzled slot)
                const int off = col*256 + (((r0 >> 3) ^ (col & 7)) << 4) + ((g & 1) << 3);
                *(uint2*)(sm + QTH_OFF + off) = uhv[bi][bj];
                *(uint2*)(sm + QTL_OFF + off) = ulv[bi][bj];
            }
            if (WXR) {   // X row-major: scattered u16 (transpose cost)
                union { uint2 u; _Float16 h[4]; } th, tl;
                th.u = uhv[bi][bj]; tl.u = ulv[bi][bj];
                #pragma unroll
                for (int q = 0; q < 4; ++q) {
                    const int rr = r0 + q;
                    const int off = swzE(rr, col);
                    *(_Float16*)(sm + PH_OFF + off) = th.h[q];
                    *(_Float16*)(sm + PL_OFF + off) = tl.h[q];
                }
            }
        }
    }
    __syncthreads();   // writes visible before next step's reads
}

__global__ __launch_bounds__(NT)
void liere_expm_mfma(const float* __restrict__ gen, float* __restrict__ out)
{
    __shared__ __align__(16) unsigned char sm[LDS_BYTES];
    const int tid = threadIdx.x;
    const int wg  = blockIdx.x;

    float px = 0.f, py = 0.f;
    if (wg > 0) {
        const int idx = wg - 1;
        px = (float)(idx / STEPS) * (1.0f/(STEPS-1));
        py = (float)(idx % STEPS) * (1.0f/(STEPS-1));
    }

    // ---- Phase 0: G = px*S0 + py*S1 (fp32), padded 132-float rows at sm+0
    float* Gp = (float*)sm;
    const float* g0 = gen;
    const float* g1 = gen + D*D;
    #pragma unroll
    for (int it = 0; it < 16; ++it) {
        const int e = tid + (it << 10);
        const int i = e >> 7, j = e & 127;
        if (i < j) {
            const float v = px*g0[e] + py*g1[e];
            Gp[i*132 + j] =  v;
            Gp[j*132 + i] = -v;
        } else if (i == j) {
            Gp[i*132 + j] = 0.f;
        }
    }
    __syncthreads();

    // ---- Phase 1: row abs-sums -> tree max -> squaring count (theta = 0.5)
    float* red = (float*)(sm + RED_OFF);
    if (tid < D) {
        float s = 0.f;
        const f32x4* rowp = (const f32x4*)&Gp[tid*132];
        #pragma unroll 8
        for (int u = 0; u < 32; ++u) {
            const f32x4 v = rowp[u];
            s += fabsf(v.x) + fabsf(v.y) + fabsf(v.z) + fabsf(v.w);
        }
        red[tid] = s;
    }
    __syncthreads();
    #pragma unroll
    for (int off = 64; off >= 1; off >>= 1) {
        if (tid < off) red[tid] = fmaxf(red[tid], red[tid + off]);
        __syncthreads();
    }
    const float m = red[0];
    int nsq = 0;
    if (m > 0.5f) nsq = (int)ceilf(log2f(m * 2.0f));
    if (nsq < 0) nsq = 0;
    const float scale = exp2f(-(float)nsq);

    // ---- Phase A: stash this lane's G values (regions about to be reused)
    float vst[16];
    #pragma unroll
    for (int it = 0; it < 16; ++it) {
        const int e = tid + (it << 10);
        vst[it] = Gp[(e>>7)*132 + (e&127)];
    }
    __syncthreads();

    // ---- Phase B: split P = G*2^-s into fp16 (h, l*2^11); init X = c7*P + c6*I
    {
        const float c7 = dC[7], c6 = dC[6];
        #pragma unroll
        for (int it = 0; it < 16; ++it) {
            const int e = tid + (it << 10);
            const int i = e >> 7, j = e & 127;
            const float p = vst[it] * scale;
            const _Float16 ph = (_Float16)p;
            const _Float16 pl = (_Float16)((p - (float)ph) * 2048.f);
            const int offP = swzE(i, j);
            *(_Float16*)(sm + PH_OFF + offP) = ph;
            *(_Float16*)(sm + PL_OFF + offP) = pl;
            const float x = c7*p + ((i == j) ? c6 : 0.f);
            const _Float16 xh = (_Float16)x;
            const _Float16 xl = (_Float16)((x - (float)xh) * 2048.f);
            const int offQ = swzE(j, i);           // X^T
            *(_Float16*)(sm + QTH_OFF + offQ) = xh;
            *(_Float16*)(sm + QTL_OFF + offQ) = xl;
        }
    }
    __syncthreads();

    const int lid = tid & 63;
    const int wid = tid >> 6;          // 0..15
    const int wr = wid >> 2, wc = wid & 3;
    const int lr = lid & 15, g = lid >> 4;
    float* gout = out + (size_t)wg * (D*D);

    // ---- Horner: X <- P*X + c_k*I (degree-7 Taylor, theta=0.5): 6 muls
    for (int kk = 5; kk >= 1; --kk)
        matmul_step<true, false, false>(sm, dC[kk], gout, wr, wc, lr, g);
    matmul_step<true, true, false>(sm, dC[0], gout, wr, wc, lr, g);

    if (nsq == 0) {   // tiny-norm blocks (incl. CLS)
        #pragma unroll
        for (int it = 0; it < 16; ++it) {
            const int e = tid + (it << 10);
            const int i = e >> 7, j = e & 127;
            const int off = swzE(i, j);
            gout[e] = (float)*(_Float16*)(sm + PH_OFF + off)
                    + (float)*(_Float16*)(sm + PL_OFF + off) * (1.0f/2048.0f);
        }
        return;
    }

    // ---- Squarings: X <- X*X; last one streams fp32 straight to HBM
    for (int t = 0; t < nsq - 1; ++t)
        matmul_step<true, true, false>(sm, 0.f, gout, wr, wc, lr, g);
    matmul_step<false, false, true>(sm, 0.f, gout, wr, wc, lr, g);
}

extern "C" void kernel_launch(void* const* d_in, const int* in_sizes, int n_in,
                              void* d_out, int out_size, void* d_ws, size_t ws_size,
                              hipStream_t stream) {
    (void)in_sizes; (void)n_in; (void)d_ws; (void)ws_size; (void)out_size;
    const float* gen = (const float*)d_in[1];   // [2,1,128,128] fp32
    float* out = (float*)d_out;                 // [1,1370,1,128,128] fp32
    liere_expm_mfma<<<NMAT, NT, 0, stream>>>(gen, out);
}